// Round 2
// baseline (46.120 us; speedup 1.0000x reference)
//
#include <hip/hip_runtime.h>
#include <math.h>

#define B_TOTAL 16384
#define NQ 512
#define NUM 3

// One wave (64 lanes) per batch element. Lane l owns conf[l*8 .. l*8+7] in
// registers. The descending-confidence scan order is independent of the
// accept decisions, so winner selection (argmax+consume) and the winner's
// pos load are software-pipelined 4 deep ahead of the accept tests: the
// ~900-cycle scattered pos-load latency hides under ~3 argmax butterflies.
__global__ __launch_bounds__(256) void greedy_nms_kernel(
    const float* __restrict__ conf,   // [B, NQ]
    const float* __restrict__ pos,    // [B, NQ, 3]
    float* __restrict__ out)          // [B, NUM, 3]
{
    const int wave = threadIdx.x >> 6;
    const int lane = threadIdx.x & 63;
    const int b = blockIdx.x * 4 + wave;
    if (b >= B_TOTAL) return;

    const float* cb = conf + (size_t)b * NQ;
    const float* pb = pos  + (size_t)b * NQ * 3;

    // coalesced vector load: lane l owns conf[l*8 .. l*8+7]
    const float4* cb4 = reinterpret_cast<const float4*>(cb);
    float4 u0 = cb4[lane * 2 + 0];
    float4 u1 = cb4[lane * 2 + 1];
    float v[8] = {u0.x, u0.y, u0.z, u0.w, u1.x, u1.y, u1.z, u1.w};

    // next_winner: wave argmax with stable tie-break (smaller n wins),
    // then consume the winner. Tree-shaped local argmax (chain depth 3).
    auto next_winner = [&]() -> int {
        float m01 = v[0]; int i01 = 0; if (v[1] > m01) { m01 = v[1]; i01 = 1; }
        float m23 = v[2]; int i23 = 2; if (v[3] > m23) { m23 = v[3]; i23 = 3; }
        float m45 = v[4]; int i45 = 4; if (v[5] > m45) { m45 = v[5]; i45 = 5; }
        float m67 = v[6]; int i67 = 6; if (v[7] > m67) { m67 = v[7]; i67 = 7; }
        if (m23 > m01) { m01 = m23; i01 = i23; }
        if (m67 > m45) { m45 = m67; i45 = i67; }
        float bestv = m01; int bests = i01;
        if (m45 > bestv) { bestv = m45; bests = i45; }
        int bestn = lane * 8 + bests;
        #pragma unroll
        for (int off = 32; off > 0; off >>= 1) {
            float ov = __shfl_xor(bestv, off);
            int   on = __shfl_xor(bestn, off);
            if (ov > bestv || (ov == bestv && on < bestn)) {
                bestv = ov; bestn = on;
            }
        }
        if (lane == (bestn >> 3)) {
            int sl = bestn & 7;
            #pragma unroll
            for (int s = 0; s < 8; ++s)
                if (sl == s) v[s] = -__builtin_inff();
        }
        return bestn;
    };

    // prime a 4-deep pipeline of (winner index, winner position)
    int   n0 = next_winner();
    float x0 = pb[n0 * 3], y0 = pb[n0 * 3 + 1], z0 = pb[n0 * 3 + 2];
    int   n1 = next_winner();
    float x1 = pb[n1 * 3], y1 = pb[n1 * 3 + 1], z1 = pb[n1 * 3 + 2];
    int   n2 = next_winner();
    float x2 = pb[n2 * 3], y2 = pb[n2 * 3 + 1], z2 = pb[n2 * 3 + 2];
    int   n3 = next_winner();
    float x3 = pb[n3 * 3], y3 = pb[n3 * 3 + 1], z3 = pb[n3 * 3 + 2];
    int found = 4;

    const float thresh = 0.78539816339744830961f; // pi/4

    // accepted set; zero vectors auto-pass (acos(0)=pi/2 >= pi/4), mirroring
    // the reference's `where(ar < count, ang, inf)` masking.
    float a0x = 0.f, a0y = 0.f, a0z = 0.f;
    float a1x = 0.f, a1y = 0.f, a1z = 0.f;
    float a2x = 0.f, a2y = 0.f, a2z = 0.f;
    int count = 0;

    #pragma unroll 1
    for (int tested = 0; tested < NQ; ++tested) {
        // accept test for the head of the pipeline (wave-uniform)
        float d0 = fminf(fabsf(a0x * x0 + a0y * y0 + a0z * z0), 1.0f);
        float d1 = fminf(fabsf(a1x * x0 + a1y * y0 + a1z * z0), 1.0f);
        float d2 = fminf(fabsf(a2x * x0 + a2y * y0 + a2z * z0), 1.0f);
        bool add = (acosf(d0) >= thresh) &&
                   (acosf(d1) >= thresh) &&
                   (acosf(d2) >= thresh);
        if (add) {
            if (count == 0)      { a0x = x0; a0y = y0; a0z = z0; }
            else if (count == 1) { a1x = x0; a1y = y0; a1z = z0; }
            else                 { a2x = x0; a2y = y0; a2z = z0; }
            if (++count == NUM) break;
        }
        // rotate the pipeline
        n0 = n1; x0 = x1; y0 = y1; z0 = z1;
        n1 = n2; x1 = x2; y1 = y2; z1 = z2;
        n2 = n3; x2 = x3; y2 = y3; z2 = z3;
        if (found < NQ) {
            n3 = next_winner();
            x3 = pb[n3 * 3]; y3 = pb[n3 * 3 + 1]; z3 = pb[n3 * 3 + 2];
            ++found;
        }
    }

    // unfilled slots -> pos[0] of this batch (reference cand stayed index 0)
    if (count < NUM) {
        float p0x = pb[0], p0y = pb[1], p0z = pb[2];
        if (count == 0) { a0x = p0x; a0y = p0y; a0z = p0z; }
        if (count <= 1) { a1x = p0x; a1y = p0y; a1z = p0z; }
        a2x = p0x; a2y = p0y; a2z = p0z;
    }

    if (lane == 0) {
        float* ob = out + (size_t)b * 9;
        ob[0] = a0x; ob[1] = a0y; ob[2] = a0z;
        ob[3] = a1x; ob[4] = a1y; ob[5] = a1z;
        ob[6] = a2x; ob[7] = a2y; ob[8] = a2z;
    }
}

extern "C" void kernel_launch(void* const* d_in, const int* in_sizes, int n_in,
                              void* d_out, int out_size, void* d_ws, size_t ws_size,
                              hipStream_t stream) {
    const float* pred_logits = (const float*)d_in[0]; // [B, NQ, 1]
    const float* pred_pos    = (const float*)d_in[1]; // [B, NQ, 3]
    float* out = (float*)d_out;                       // [B, NUM, 3]

    const int waves_per_block = 4;
    const int grid = (B_TOTAL + waves_per_block - 1) / waves_per_block; // 4096
    greedy_nms_kernel<<<grid, 256, 0, stream>>>(pred_logits, pred_pos, out);
}

// Round 3
// 29.135 us; speedup vs baseline: 1.5830x; 1.5830x over previous
//
#include <hip/hip_runtime.h>
#include <math.h>

#define B_TOTAL 16384
#define NQ 512
#define NUM 3

// One wave (64 lanes) per batch. Lane l owns conf[l*8 .. l*8+7] as monotone
// u32 keys. Greedy loop: packed-u64 wave argmax (key<<32 | 511-n gives
// stable smaller-index tie-break), consume (key=0), angular accept test via
// |dot| <= cos(pi/4) with a guard band falling back to exact acosf so the
// decision is bit-identical to the reference at the boundary.
__global__ __launch_bounds__(256) void greedy_nms_kernel(
    const float* __restrict__ conf,   // [B, NQ]
    const float* __restrict__ pos,    // [B, NQ, 3]
    float* __restrict__ out)          // [B, NUM, 3]
{
    const int wave = threadIdx.x >> 6;
    const int lane = threadIdx.x & 63;
    const int b = (blockIdx.x << 2) + wave;   // grid*4 == B_TOTAL exactly

    const float* cb = conf + (size_t)b * NQ;
    const float* pb = pos  + (size_t)b * NQ * 3;

    // coalesced vector load: lane l owns conf[l*8 .. l*8+7]
    const float4* cb4 = reinterpret_cast<const float4*>(cb);
    float4 u0 = cb4[lane * 2 + 0];
    float4 u1 = cb4[lane * 2 + 1];
    float fv[8] = {u0.x, u0.y, u0.z, u0.w, u1.x, u1.y, u1.z, u1.w};

    // monotone float->u32 key (bigger float => bigger key); no NaNs in input
    unsigned k[8];
    #pragma unroll
    for (int s = 0; s < 8; ++s) {
        int bi = __float_as_int(fv[s]);
        k[s] = (unsigned)bi ^ ((unsigned)(bi >> 31) | 0x80000000u);
    }

    // wave argmax with stable tie-break (smaller n wins), then consume.
    auto next_winner = [&]() -> int {
        unsigned m01 = k[0]; int i01 = 0; if (k[1] > m01) { m01 = k[1]; i01 = 1; }
        unsigned m23 = k[2]; int i23 = 2; if (k[3] > m23) { m23 = k[3]; i23 = 3; }
        unsigned m45 = k[4]; int i45 = 4; if (k[5] > m45) { m45 = k[5]; i45 = 5; }
        unsigned m67 = k[6]; int i67 = 6; if (k[7] > m67) { m67 = k[7]; i67 = 7; }
        if (m23 > m01) { m01 = m23; i01 = i23; }
        if (m67 > m45) { m45 = m67; i45 = i67; }
        if (m45 > m01) { m01 = m45; i01 = i45; }
        // pack: hi32 = key, lo32 = 511-n  (tie -> larger lo -> smaller n)
        unsigned long long key =
            ((unsigned long long)m01 << 32) |
            (unsigned)(NQ - 1 - ((lane << 3) + i01));
        #pragma unroll
        for (int off = 32; off > 0; off >>= 1) {
            unsigned long long o = __shfl_xor(key, off);
            if (o > key) key = o;
        }
        int n = NQ - 1 - (int)(unsigned)key;   // low 32 bits hold 511-n
        if ((n >> 3) == lane) {
            const int sl = n & 7;
            #pragma unroll
            for (int s = 0; s < 8; ++s)
                if (sl == s) k[s] = 0u;        // 0 < every real key
        }
        return n;
    };

    const float TH  = 0.78539816339744830961f; // f32 -> 0.78539818f (ref thresh)
    const float CLO = 0.70710478f;             // cos(pi/4) - ~2e-6
    const float CHI = 0.70710878f;             // cos(pi/4) + ~2e-6

    // accepted set; zero vectors auto-pass (dot 0 <= CLO), mirroring the
    // reference's `where(ar < count, ang, inf)` masking.
    float a0x = 0.f, a0y = 0.f, a0z = 0.f;
    float a1x = 0.f, a1y = 0.f, a1z = 0.f;
    float a2x = 0.f, a2y = 0.f, a2z = 0.f;
    int count = 0;

    #pragma unroll 1
    for (int t = 0; t < NQ; ++t) {
        const int n = next_winner();
        const float px = pb[n * 3 + 0];
        const float py = pb[n * 3 + 1];
        const float pz = pb[n * 3 + 2];

        const float d0 = fabsf(a0x * px + a0y * py + a0z * pz);
        const float d1 = fabsf(a1x * px + a1y * py + a1z * pz);
        const float d2 = fabsf(a2x * px + a2y * py + a2z * pz);
        const float dm = fmaxf(d0, fmaxf(d1, d2));

        bool add;
        if (dm <= CLO) {
            add = true;                         // all angles clearly >= pi/4
        } else if (dm >= CHI) {
            add = false;                        // some angle clearly < pi/4
        } else {
            // borderline (prob ~1e-5): exact reference formula
            add = (acosf(fminf(d0, 1.f)) >= TH) &&
                  (acosf(fminf(d1, 1.f)) >= TH) &&
                  (acosf(fminf(d2, 1.f)) >= TH);
        }

        if (add) {
            if (count == 0)      { a0x = px; a0y = py; a0z = pz; }
            else if (count == 1) { a1x = px; a1y = py; a1z = pz; }
            else                 { a2x = px; a2y = py; a2z = pz; }
            if (++count == NUM) break;
        }
    }

    // unfilled slots -> pos[0] of this batch (reference cand stayed index 0)
    if (count < NUM) {
        float p0x = pb[0], p0y = pb[1], p0z = pb[2];
        if (count == 0) { a0x = p0x; a0y = p0y; a0z = p0z; }
        if (count <= 1) { a1x = p0x; a1y = p0y; a1z = p0z; }
        a2x = p0x; a2y = p0y; a2z = p0z;
    }

    if (lane == 0) {
        float* ob = out + (size_t)b * 9;
        ob[0] = a0x; ob[1] = a0y; ob[2] = a0z;
        ob[3] = a1x; ob[4] = a1y; ob[5] = a1z;
        ob[6] = a2x; ob[7] = a2y; ob[8] = a2z;
    }
}

extern "C" void kernel_launch(void* const* d_in, const int* in_sizes, int n_in,
                              void* d_out, int out_size, void* d_ws, size_t ws_size,
                              hipStream_t stream) {
    const float* pred_logits = (const float*)d_in[0]; // [B, NQ, 1]
    const float* pred_pos    = (const float*)d_in[1]; // [B, NQ, 3]
    float* out = (float*)d_out;                       // [B, NUM, 3]

    const int grid = B_TOTAL / 4;                     // 4 waves/block
    greedy_nms_kernel<<<grid, 256, 0, stream>>>(pred_logits, pred_pos, out);
}